// Round 1
// baseline (301.000 us; speedup 1.0000x reference)
//
#include <hip/hip_runtime.h>
#include <hip/hip_bf16.h>

#define Bn 4
#define Cn 128
#define Ln 8000
#define Hn 512
#define NROW 256
#define EPSf 1e-8f

typedef unsigned short u16;

__device__ __forceinline__ float bf2f(unsigned v) {
  return __uint_as_float(v << 16);
}
__device__ __forceinline__ u16 f2bf(float f) {
  unsigned u = __float_as_uint(f);
  unsigned r = (u + 0x7fffu + ((u >> 16) & 1u)) >> 16;
  return (u16)r;
}

// ---------------- prep: transpose weights for coalesced staging ----------------
__global__ void k0_prep(const float* __restrict__ W1, const float* __restrict__ Wout,
                        const float* __restrict__ Wskip,
                        float* __restrict__ W1t, float* __restrict__ Wcatt,
                        float* __restrict__ Wsum)
{
  const int bid = blockIdx.x, tid = threadIdx.x;
  if (bid < 64) {
    const int base = (bid * 256 + tid) * 4;
#pragma unroll
    for (int t = 0; t < 4; ++t) {
      int i = base + t;            // 0..65535
      int k = i >> 9, h = i & 511; // W1t[k][h] = W1[h][k]
      W1t[i] = W1[h * Cn + k];
    }
  } else if (bid < 192) {
    const int base = ((bid - 64) * 256 + tid) * 4;
#pragma unroll
    for (int t = 0; t < 4; ++t) {
      int j = base + t;            // 0..131071
      int k = j >> 8, c = j & 255; // Wcatt[k][c]
      Wcatt[j] = (c < Cn) ? Wout[c * Hn + k] : Wskip[(c - Cn) * Hn + k];
    }
  } else {
    const int r = tid;
    float s = 0.f;
    const float* Wp = (r < Cn) ? (Wout + (size_t)r * Hn) : (Wskip + (size_t)(r - Cn) * Hn);
    for (int k = 0; k < Hn; ++k) s += Wp[k];
    Wsum[r] = s;
  }
}

// ---------------- K1: h = prelu(W1 @ x + b1), + channel sums ----------------
__global__ __launch_bounds__(256, 3)
void k1_gemm1(const float* __restrict__ x, const float* __restrict__ W1t,
              const float* __restrict__ b1, const float* __restrict__ a1p,
              u16* __restrict__ hbuf, float* __restrict__ sum1, float* __restrict__ sumsq1)
{
  __shared__ float xs[Cn][32];     // 16 KB
  __shared__ float wt[16][Hn];     // 32 KB
  __shared__ float red_s[4][4][8];
  __shared__ float red_q[4][4][8];

  const int bidx = blockIdx.x;
  const int b = bidx / (Ln / 32);
  const int l0 = (bidx % (Ln / 32)) * 32;
  const int tid = threadIdx.x;

  {
    const float* xb = x + (size_t)b * Cn * Ln + l0;
#pragma unroll
    for (int p = 0; p < 4; ++p) {
      int lin = p * 1024 + tid * 4;
      int row = lin >> 5, pos = lin & 31;
      float4 v = *reinterpret_cast<const float4*>(xb + (size_t)row * Ln + pos);
      *reinterpret_cast<float4*>(&xs[0][0] + lin) = v;
    }
  }

  float acc[8][8];
#pragma unroll
  for (int i = 0; i < 8; ++i)
#pragma unroll
    for (int j = 0; j < 8; ++j) acc[i][j] = 0.f;

  const int hg = tid >> 2;   // 0..63 -> rows hg*8..+7 (512 rows)
  const int lg = tid & 3;    // 0..3  -> l = l0 + lg*8 + j
  const int h0 = hg * 8;
  const int lb = lg * 8;

  for (int kt = 0; kt < Cn; kt += 16) {
    __syncthreads();
#pragma unroll
    for (int p = 0; p < 8; ++p) {
      int lin = p * 1024 + tid * 4;
      float4 v = *reinterpret_cast<const float4*>(W1t + kt * Hn + lin);
      *reinterpret_cast<float4*>(&wt[0][0] + lin) = v;
    }
    __syncthreads();
#pragma unroll 4
    for (int kk = 0; kk < 16; ++kk) {
      float4 w0 = *reinterpret_cast<const float4*>(&wt[kk][h0]);
      float4 w1 = *reinterpret_cast<const float4*>(&wt[kk][h0 + 4]);
      float4 x0 = *reinterpret_cast<const float4*>(&xs[kt + kk][lb]);
      float4 x1 = *reinterpret_cast<const float4*>(&xs[kt + kk][lb + 4]);
      float wv[8] = {w0.x, w0.y, w0.z, w0.w, w1.x, w1.y, w1.z, w1.w};
      float xv[8] = {x0.x, x0.y, x0.z, x0.w, x1.x, x1.y, x1.z, x1.w};
#pragma unroll
      for (int i = 0; i < 8; ++i)
#pragma unroll
        for (int j = 0; j < 8; ++j)
          acc[i][j] = fmaf(wv[i], xv[j], acc[i][j]);
    }
  }

  const float a1v = a1p[0];
  float s[8], q[8];
#pragma unroll
  for (int j = 0; j < 8; ++j) { s[j] = 0.f; q[j] = 0.f; }

#pragma unroll
  for (int i = 0; i < 8; ++i) {
    const int hh = h0 + i;
    const float bias = b1[hh];
    unsigned pk[4];
#pragma unroll
    for (int jj = 0; jj < 4; ++jj) {
      float v0 = acc[i][jj * 2] + bias;
      v0 = v0 >= 0.f ? v0 : a1v * v0;
      float v1 = acc[i][jj * 2 + 1] + bias;
      v1 = v1 >= 0.f ? v1 : a1v * v1;
      s[jj * 2] += v0;     q[jj * 2] += v0 * v0;
      s[jj * 2 + 1] += v1; q[jj * 2 + 1] += v1 * v1;
      pk[jj] = (unsigned)f2bf(v0) | ((unsigned)f2bf(v1) << 16);
    }
    uint4 st; st.x = pk[0]; st.y = pk[1]; st.z = pk[2]; st.w = pk[3];
    *reinterpret_cast<uint4*>(hbuf + ((size_t)b * Hn + hh) * Ln + l0 + lb) = st;
  }

#pragma unroll
  for (int m = 4; m < 64; m <<= 1) {
#pragma unroll
    for (int j = 0; j < 8; ++j) {
      s[j] += __shfl_xor(s[j], m);
      q[j] += __shfl_xor(q[j], m);
    }
  }
  const int wid = tid >> 6;
  const int lane = tid & 63;
  if (lane < 4) {
#pragma unroll
    for (int j = 0; j < 8; ++j) { red_s[wid][lane][j] = s[j]; red_q[wid][lane][j] = q[j]; }
  }
  __syncthreads();
  if (tid < 32) {
    const int lgg = tid >> 3, j = tid & 7;
    float ts = 0.f, tq = 0.f;
#pragma unroll
    for (int w = 0; w < 4; ++w) { ts += red_s[w][lgg][j]; tq += red_q[w][lgg][j]; }
    sum1[b * Ln + l0 + tid] = ts;
    sumsq1[b * Ln + l0 + tid] = tq;
  }
}

// ---------------- K2: causal scan -> mean/rstd ----------------
__global__ void k2_scan(const float* __restrict__ sum, const float* __restrict__ sumsq,
                        float* __restrict__ mean, float* __restrict__ rstd)
{
  const int b = blockIdx.x;
  const int tid = threadIdx.x;
  const int lane = tid & 63;
  const int wid = tid >> 6;
  __shared__ float wsm[4], wq[4];
  __shared__ float carry[2];
  if (tid == 0) { carry[0] = 0.f; carry[1] = 0.f; }
  __syncthreads();
  for (int base = 0; base < Ln; base += 256) {
    const int l = base + tid;
    float v = (l < Ln) ? sum[b * Ln + l] : 0.f;
    float q = (l < Ln) ? sumsq[b * Ln + l] : 0.f;
#pragma unroll
    for (int off = 1; off < 64; off <<= 1) {
      float tv = __shfl_up(v, off);
      float tq = __shfl_up(q, off);
      if (lane >= off) { v += tv; q += tq; }
    }
    if (lane == 63) { wsm[wid] = v; wq[wid] = q; }
    __syncthreads();
    float cs = carry[0], cq = carry[1];
    for (int w = 0; w < wid; ++w) { cs += wsm[w]; cq += wq[w]; }
    v += cs; q += cq;
    if (l < Ln) {
      float cnt = 512.f * (float)(l + 1);
      float mn = v / cnt;
      float var = q / cnt - mn * mn;
      var = fmaxf(var, 0.f);
      mean[b * Ln + l] = mn;
      rstd[b * Ln + l] = rsqrtf(var + EPSf);
    }
    __syncthreads();
    if (tid == 0) {
      carry[0] += wsm[0] + wsm[1] + wsm[2] + wsm[3];
      carry[1] += wq[0] + wq[1] + wq[2] + wq[3];
    }
    __syncthreads();
  }
}

// ---------------- K3: g = prelu(dwconv(cln1(h))), + channel sums ----------------
__global__ __launch_bounds__(256, 4)
void k3_conv(const u16* __restrict__ hbuf, const float* __restrict__ mean1,
             const float* __restrict__ rstd1, const float* __restrict__ dw,
             const float* __restrict__ db, const float* __restrict__ a2p,
             u16* __restrict__ gbuf, float* __restrict__ sum2, float* __restrict__ sumsq2)
{
  __shared__ float m1s[40], r1s[40];
  __shared__ float red_s[4][4][8];
  __shared__ float red_q[4][4][8];
  const int bidx = blockIdx.x;
  const int b = bidx / (Ln / 32);
  const int l0 = (bidx % (Ln / 32)) * 32;
  const int tid = threadIdx.x;
  if (tid < 40) {
    int p = l0 - 4 + tid;
    bool ok = (p >= 0) && (p < Ln);
    m1s[tid] = ok ? mean1[b * Ln + p] : 0.f;
    r1s[tid] = ok ? rstd1[b * Ln + p] : 0.f;
  }
  __syncthreads();
  const int hg = tid >> 2;
  const int lg = tid & 3;
  const int lb = lg * 8;
  const float a2v = a2p[0];
  float s[8], q[8];
#pragma unroll
  for (int j = 0; j < 8; ++j) { s[j] = 0.f; q[j] = 0.f; }

#pragma unroll
  for (int i = 0; i < 8; ++i) {
    const int hh = hg * 8 + i;
    const u16* hrow = hbuf + ((size_t)b * Hn + hh) * Ln;
    float nh[16];
#pragma unroll
    for (int qd = 0; qd < 4; ++qd) {
      const int p = l0 + lb - 4 + qd * 4;
      const int e = qd * 4;
      if (p >= 0 && p + 3 < Ln) {   // quads are all-valid or all-pad (L%4==0, offsets %4==0)
        uint2 raw = *reinterpret_cast<const uint2*>(hrow + p);
        nh[e + 0] = (bf2f(raw.x & 0xffffu) - m1s[lb + e + 0]) * r1s[lb + e + 0];
        nh[e + 1] = (bf2f(raw.x >> 16)     - m1s[lb + e + 1]) * r1s[lb + e + 1];
        nh[e + 2] = (bf2f(raw.y & 0xffffu) - m1s[lb + e + 2]) * r1s[lb + e + 2];
        nh[e + 3] = (bf2f(raw.y >> 16)     - m1s[lb + e + 3]) * r1s[lb + e + 3];
      } else {
        nh[e + 0] = 0.f; nh[e + 1] = 0.f; nh[e + 2] = 0.f; nh[e + 3] = 0.f;
      }
    }
    const float d0 = dw[hh * 3 + 0], d1 = dw[hh * 3 + 1], d2 = dw[hh * 3 + 2];
    const float bias = db[hh];
    unsigned pk[4];
#pragma unroll
    for (int jj = 0; jj < 4; ++jj) {
      const int j0 = jj * 2, j1 = jj * 2 + 1;
      float v0 = fmaf(d0, nh[j0], fmaf(d1, nh[j0 + 4], fmaf(d2, nh[j0 + 8], bias)));
      v0 = v0 >= 0.f ? v0 : a2v * v0;
      float v1 = fmaf(d0, nh[j1], fmaf(d1, nh[j1 + 4], fmaf(d2, nh[j1 + 8], bias)));
      v1 = v1 >= 0.f ? v1 : a2v * v1;
      s[j0] += v0; q[j0] += v0 * v0;
      s[j1] += v1; q[j1] += v1 * v1;
      pk[jj] = (unsigned)f2bf(v0) | ((unsigned)f2bf(v1) << 16);
    }
    uint4 st; st.x = pk[0]; st.y = pk[1]; st.z = pk[2]; st.w = pk[3];
    *reinterpret_cast<uint4*>(gbuf + ((size_t)b * Hn + hh) * Ln + l0 + lb) = st;
  }

#pragma unroll
  for (int m = 4; m < 64; m <<= 1) {
#pragma unroll
    for (int j = 0; j < 8; ++j) {
      s[j] += __shfl_xor(s[j], m);
      q[j] += __shfl_xor(q[j], m);
    }
  }
  const int wid = tid >> 6;
  const int lane = tid & 63;
  if (lane < 4) {
#pragma unroll
    for (int j = 0; j < 8; ++j) { red_s[wid][lane][j] = s[j]; red_q[wid][lane][j] = q[j]; }
  }
  __syncthreads();
  if (tid < 32) {
    const int lgg = tid >> 3, j = tid & 7;
    float ts = 0.f, tq = 0.f;
#pragma unroll
    for (int w = 0; w < 4; ++w) { ts += red_s[w][lgg][j]; tq += red_q[w][lgg][j]; }
    sum2[b * Ln + l0 + tid] = ts;
    sumsq2[b * Ln + l0 + tid] = tq;
  }
}

// ---------------- K5: out/skip = Wcat @ g with folded cln2 + residual ----------------
__global__ __launch_bounds__(256, 3)
void k5_gemm2(const u16* __restrict__ gbuf, const float* __restrict__ Wcatt,
              const float* __restrict__ Wsum, const float* __restrict__ bout,
              const float* __restrict__ bskip, const float* __restrict__ mean2,
              const float* __restrict__ rstd2, const float* __restrict__ x,
              float* __restrict__ outp)
{
  __shared__ float gs[32][64];     // 8 KB
  __shared__ float wct[32][NROW];  // 32 KB
  __shared__ float m2s[64], r2s[64];
  const int bidx = blockIdx.x;
  const int b = bidx / (Ln / 64);
  const int l0 = (bidx % (Ln / 64)) * 64;
  const int tid = threadIdx.x;
  if (tid < 64) {
    m2s[tid] = mean2[b * Ln + l0 + tid];
    r2s[tid] = rstd2[b * Ln + l0 + tid];
  }
  const int hg = tid >> 3;  // 0..31 -> rows hg*8..+7 (256 rows)
  const int lg = tid & 7;   // 0..7  -> l = l0 + lg*8 + j
  float acc[8][8];
#pragma unroll
  for (int i = 0; i < 8; ++i)
#pragma unroll
    for (int j = 0; j < 8; ++j) acc[i][j] = 0.f;

  for (int kt = 0; kt < Hn; kt += 32) {
    __syncthreads();
#pragma unroll
    for (int p = 0; p < 2; ++p) {
      int lin = p * 1024 + tid * 4;
      int row = lin >> 6, pos = lin & 63;
      uint2 raw = *reinterpret_cast<const uint2*>(gbuf + ((size_t)b * Hn + kt + row) * Ln + l0 + pos);
      float4 v;
      v.x = bf2f(raw.x & 0xffffu);
      v.y = bf2f(raw.x >> 16);
      v.z = bf2f(raw.y & 0xffffu);
      v.w = bf2f(raw.y >> 16);
      *reinterpret_cast<float4*>(&gs[0][0] + lin) = v;
    }
#pragma unroll
    for (int p = 0; p < 8; ++p) {
      int lin = p * 1024 + tid * 4;
      float4 v = *reinterpret_cast<const float4*>(Wcatt + kt * NROW + lin);
      *reinterpret_cast<float4*>(&wct[0][0] + lin) = v;
    }
    __syncthreads();
#pragma unroll 4
    for (int kk = 0; kk < 32; ++kk) {
      float4 w0 = *reinterpret_cast<const float4*>(&wct[kk][hg * 8]);
      float4 w1 = *reinterpret_cast<const float4*>(&wct[kk][hg * 8 + 4]);
      float4 g0 = *reinterpret_cast<const float4*>(&gs[kk][lg * 8]);
      float4 g1 = *reinterpret_cast<const float4*>(&gs[kk][lg * 8 + 4]);
      float wv[8] = {w0.x, w0.y, w0.z, w0.w, w1.x, w1.y, w1.z, w1.w};
      float gv[8] = {g0.x, g0.y, g0.z, g0.w, g1.x, g1.y, g1.z, g1.w};
#pragma unroll
      for (int i = 0; i < 8; ++i)
#pragma unroll
        for (int j = 0; j < 8; ++j)
          acc[i][j] = fmaf(wv[i], gv[j], acc[i][j]);
    }
  }

  const size_t OUTOFF = (size_t)Bn * Cn * Ln;
#pragma unroll
  for (int i = 0; i < 8; ++i) {
    const int r = hg * 8 + i;
    const float wsum = Wsum[r];
    float o[8];
    if (r < Cn) {
      const float* xr = x + ((size_t)b * Cn + r) * Ln + l0 + lg * 8;
      float4 x0 = *reinterpret_cast<const float4*>(xr);
      float4 x1 = *reinterpret_cast<const float4*>(xr + 4);
      float xv[8] = {x0.x, x0.y, x0.z, x0.w, x1.x, x1.y, x1.z, x1.w};
      const float bias = bout[r];
#pragma unroll
      for (int j = 0; j < 8; ++j) {
        int ll = lg * 8 + j;
        o[j] = r2s[ll] * (acc[i][j] - m2s[ll] * wsum) + bias + xv[j];
      }
      float* op = outp + ((size_t)b * Cn + r) * Ln + l0 + lg * 8;
      float4 s0, s1;
      s0.x = o[0]; s0.y = o[1]; s0.z = o[2]; s0.w = o[3];
      s1.x = o[4]; s1.y = o[5]; s1.z = o[6]; s1.w = o[7];
      *reinterpret_cast<float4*>(op) = s0;
      *reinterpret_cast<float4*>(op + 4) = s1;
    } else {
      const float bias = bskip[r - Cn];
#pragma unroll
      for (int j = 0; j < 8; ++j) {
        int ll = lg * 8 + j;
        o[j] = r2s[ll] * (acc[i][j] - m2s[ll] * wsum) + bias;
      }
      float* op = outp + OUTOFF + ((size_t)b * Cn + (r - Cn)) * Ln + l0 + lg * 8;
      float4 s0, s1;
      s0.x = o[0]; s0.y = o[1]; s0.z = o[2]; s0.w = o[3];
      s1.x = o[4]; s1.y = o[5]; s1.z = o[6]; s1.w = o[7];
      *reinterpret_cast<float4*>(op) = s0;
      *reinterpret_cast<float4*>(op + 4) = s1;
    }
  }
}

extern "C" void kernel_launch(void* const* d_in, const int* in_sizes, int n_in,
                              void* d_out, int out_size, void* d_ws, size_t ws_size,
                              hipStream_t stream)
{
  const float* x     = (const float*)d_in[0];
  const float* W1    = (const float*)d_in[1];
  const float* b1    = (const float*)d_in[2];
  const float* dw    = (const float*)d_in[3];
  const float* db    = (const float*)d_in[4];
  const float* Wout  = (const float*)d_in[5];
  const float* bout  = (const float*)d_in[6];
  const float* Wskip = (const float*)d_in[7];
  const float* bskip = (const float*)d_in[8];
  const float* a1    = (const float*)d_in[9];
  const float* a2    = (const float*)d_in[10];
  float* outp = (float*)d_out;

  char* ws = (char*)d_ws;
  u16* hbuf   = (u16*)(ws);                 // 16,384,000 bf16 = 32,768,000 B
  u16* gbuf   = (u16*)(ws + 32768000);      // 32,768,000 B
  float* W1t    = (float*)(ws + 65536000);  // 65536 f
  float* Wcatt  = (float*)(ws + 65798144);  // 131072 f
  float* Wsum   = (float*)(ws + 66322432);  // 256 f
  float* sum1   = (float*)(ws + 66323456);  // 32000 f each below
  float* sumsq1 = (float*)(ws + 66451456);
  float* mean1  = (float*)(ws + 66579456);
  float* rstd1  = (float*)(ws + 66707456);
  float* sum2   = (float*)(ws + 66835456);
  float* sumsq2 = (float*)(ws + 66963456);
  float* mean2  = (float*)(ws + 67091456);
  float* rstd2  = (float*)(ws + 67219456);
  (void)in_sizes; (void)n_in; (void)out_size; (void)ws_size;

  hipLaunchKernelGGL(k0_prep, dim3(193), dim3(256), 0, stream,
                     W1, Wout, Wskip, W1t, Wcatt, Wsum);
  hipLaunchKernelGGL(k1_gemm1, dim3(Bn * (Ln / 32)), dim3(256), 0, stream,
                     x, W1t, b1, a1, hbuf, sum1, sumsq1);
  hipLaunchKernelGGL(k2_scan, dim3(Bn), dim3(256), 0, stream,
                     sum1, sumsq1, mean1, rstd1);
  hipLaunchKernelGGL(k3_conv, dim3(Bn * (Ln / 32)), dim3(256), 0, stream,
                     hbuf, mean1, rstd1, dw, db, a2, gbuf, sum2, sumsq2);
  hipLaunchKernelGGL(k2_scan, dim3(Bn), dim3(256), 0, stream,
                     sum2, sumsq2, mean2, rstd2);
  hipLaunchKernelGGL(k5_gemm2, dim3(Bn * (Ln / 64)), dim3(256), 0, stream,
                     gbuf, Wcatt, Wsum, bout, bskip, mean2, rstd2, x, outp);
}

// Round 2
// 162.791 us; speedup vs baseline: 1.8490x; 1.8490x over previous
//
#include <hip/hip_runtime.h>

typedef unsigned short u16;
typedef unsigned int u32;
typedef __attribute__((ext_vector_type(8))) short bf16x8;
typedef __attribute__((ext_vector_type(4))) float f32x4;

#define Bn 4
#define Cn 128
#define Hn 512
#define Ln 8000
#define EPSf 1e-8f

__device__ __forceinline__ float bf2f(u32 v) { return __uint_as_float(v << 16); }
__device__ __forceinline__ u32 f2bf(float f) {
  u32 u = __float_as_uint(f);
  return (u + 0x7fffu + ((u >> 16) & 1u)) >> 16;
}
__device__ __forceinline__ void gl16(const void* g, void* l) {
  __builtin_amdgcn_global_load_lds((const __attribute__((address_space(1))) u32*)g,
                                   (__attribute__((address_space(3))) u32*)l, 16, 0, 0);
}

// ---------------- k0: weight prep (bf16 + pre-swizzled images) ----------------
// W1b:  LDS image [512 h][128 k] bf16, elem (h,k) at byte h*256 + ((k*2)^((h&7)<<4))
// Wcatb: per K-tile kt(8): [256 c][64 kk] bf16, byte kt*32768 + c*128 + ((kk*2)^((c&7)<<4))
__global__ void k0_prep(const float* __restrict__ W1, const float* __restrict__ Wout,
                        const float* __restrict__ Wskip,
                        u16* __restrict__ W1b, u16* __restrict__ Wcatb,
                        float* __restrict__ Wsum)
{
  const int bid = blockIdx.x, tid = threadIdx.x;
  if (bid < 64) {
    const int base = (bid * 256 + tid) * 4;
#pragma unroll
    for (int t = 0; t < 4; ++t) {
      int i = base + t;            // 0..65535
      int h = i >> 7, k = i & 127;
      int dbyte = h * 256 + (((k * 2) ^ ((h & 7) << 4)));
      W1b[dbyte >> 1] = (u16)f2bf(W1[h * Cn + k]);
    }
  } else if (bid < 192) {
    const int base = ((bid - 64) * 256 + tid) * 4;
#pragma unroll
    for (int t = 0; t < 4; ++t) {
      int j = base + t;            // 0..131071
      int kt = j >> 14, r = j & 16383, c = r >> 6, kk = r & 63;
      int k = kt * 64 + kk;
      float v = (c < Cn) ? Wout[c * Hn + k] : Wskip[(c - Cn) * Hn + k];
      int dbyte = kt * 32768 + c * 128 + (((kk * 2) ^ ((c & 7) << 4)));
      Wcatb[dbyte >> 1] = (u16)f2bf(v);
    }
  } else {
    const int c = tid;
    const float* Wp = (c < Cn) ? (Wout + (size_t)c * Hn) : (Wskip + (size_t)(c - Cn) * Hn);
    float s = 0.f;
    for (int k = 0; k < Hn; ++k) s += Wp[k];
    Wsum[c] = s;
  }
}

// ---------------- ktr: x[b][c][l] f32 -> xTb[b][l][c] bf16 (pre-swizzled rows) ----------------
__global__ __launch_bounds__(256, 4)
void ktr(const float* __restrict__ x, u16* __restrict__ xTb)
{
  __shared__ char xls[32768];   // [128 c][256B row], float4 at c*256 + ((lq4*16)^((c&7)<<4))
  const int bidx = blockIdx.x;
  const int b = bidx / 125;
  const int l0 = (bidx % 125) * 64;
  const int tid = threadIdx.x;
#pragma unroll
  for (int p = 0; p < 8; ++p) {
    int i = tid + p * 256;
    int c = i >> 4, lq4 = i & 15;
    float4 v = *reinterpret_cast<const float4*>(x + ((size_t)(b * Cn + c)) * Ln + l0 + lq4 * 4);
    *reinterpret_cast<float4*>(xls + c * 256 + (((lq4 * 16) ^ ((c & 7) << 4)))) = v;
  }
  __syncthreads();
#pragma unroll
  for (int p = 0; p < 4; ++p) {
    int u = tid + p * 256;
    int l = u & 63, u16i = u >> 6;
    u32 pk[4];
#pragma unroll
    for (int pp = 0; pp < 4; ++pp) {
      float f0, f1;
      {
        int c = u16i * 8 + pp * 2;
        int byte0 = c * 256 + ((((l >> 2) * 16) ^ ((c & 7) << 4))) + (l & 3) * 4;
        f0 = *reinterpret_cast<const float*>(xls + byte0);
        int c1 = c + 1;
        int byte1 = c1 * 256 + ((((l >> 2) * 16) ^ ((c1 & 7) << 4))) + (l & 3) * 4;
        f1 = *reinterpret_cast<const float*>(xls + byte1);
      }
      pk[pp] = f2bf(f0) | (f2bf(f1) << 16);
    }
    uint4 st; st.x = pk[0]; st.y = pk[1]; st.z = pk[2]; st.w = pk[3];
    size_t rowb = ((size_t)(b * Ln + l0 + l)) * 256;
    *reinterpret_cast<uint4*>((char*)xTb + rowb + (((u16i * 16) ^ ((l & 7) << 4)))) = st;
  }
}

// ---------------- k1: h = prelu(W1@x + b1) via MFMA; writes hT[b][l][h] bf16 + sums ----------------
__global__ __launch_bounds__(256, 1)
void k1_gemm1(const u16* __restrict__ xTb, const u16* __restrict__ W1b,
              const float* __restrict__ b1, const float* __restrict__ a1p,
              u16* __restrict__ hT, float* __restrict__ sum1, float* __restrict__ sumsq1)
{
  __shared__ char W1s[131072];
  __shared__ char xs[16384];
  __shared__ float b1s[512];
  __shared__ float red_s[4][4][16];
  __shared__ float red_q[4][4][16];

  const int bidx = blockIdx.x;
  const int b = bidx / 125;
  const int l0 = (bidx % 125) * 64;
  const int tid = threadIdx.x;
  const int ln = tid & 63, w = tid >> 6;
  const int ln15 = ln & 15, lq = ln >> 4;

  // stage W1 image (128 chunks of 1KB), x tile (16 chunks), b1
  for (int i = 0; i < 32; ++i) {
    int chunk = w * 32 + i;
    gl16((const char*)W1b + chunk * 1024 + ln * 16, W1s + chunk * 1024);
  }
  {
    size_t gbase = ((size_t)(b * Ln + l0)) * 256;
#pragma unroll
    for (int i = 0; i < 4; ++i) {
      int chunk = w * 4 + i;
      gl16((const char*)xTb + gbase + chunk * 1024 + ln * 16, xs + chunk * 1024);
    }
  }
  b1s[tid] = b1[tid];
  b1s[tid + 256] = b1[tid + 256];
  __syncthreads();

  const int h0w = w * 128;
  f32x4 acc[8][4];
  const f32x4 z4 = {0.f, 0.f, 0.f, 0.f};
#pragma unroll
  for (int i = 0; i < 8; ++i)
#pragma unroll
    for (int j = 0; j < 4; ++j) acc[i][j] = z4;

#pragma unroll
  for (int kf = 0; kf < 4; ++kf) {
    bf16x8 bfr[4];
#pragma unroll
    for (int cf = 0; cf < 4; ++cf) {
      int brow = cf * 16 + ln15;
      int off = ((kf * 64 + lq * 16) ^ ((brow & 7) << 4));
      bfr[cf] = *reinterpret_cast<const bf16x8*>(xs + brow * 256 + off);
    }
#pragma unroll
    for (int rf = 0; rf < 8; ++rf) {
      int arow = h0w + rf * 16 + ln15;
      int aoff = ((kf * 64 + lq * 16) ^ ((arow & 7) << 4));
      bf16x8 afr = *reinterpret_cast<const bf16x8*>(W1s + arow * 256 + aoff);
#pragma unroll
      for (int cf = 0; cf < 4; ++cf)
        acc[rf][cf] = __builtin_amdgcn_mfma_f32_16x16x32_bf16(afr, bfr[cf], acc[rf][cf], 0, 0, 0);
    }
  }

  // epilogue: bias + prelu, store hT, per-l sums
  const float a1v = a1p[0];
  float s[4], q[4];
#pragma unroll
  for (int cf = 0; cf < 4; ++cf) { s[cf] = 0.f; q[cf] = 0.f; }

#pragma unroll
  for (int rf = 0; rf < 8; ++rf) {
    const int hbase = h0w + rf * 16 + lq * 4;
    float bv[4];
#pragma unroll
    for (int r = 0; r < 4; ++r) bv[r] = b1s[hbase + r];
#pragma unroll
    for (int cf = 0; cf < 4; ++cf) {
      const int l = l0 + cf * 16 + ln15;
      float v[4];
#pragma unroll
      for (int r = 0; r < 4; ++r) {
        float t = acc[rf][cf][r] + bv[r];
        t = t >= 0.f ? t : a1v * t;
        v[r] = t;
        s[cf] += t; q[cf] += t * t;
      }
      uint2 st;
      st.x = f2bf(v[0]) | (f2bf(v[1]) << 16);
      st.y = f2bf(v[2]) | (f2bf(v[3]) << 16);
      *reinterpret_cast<uint2*>((char*)hT + ((size_t)(b * Ln + l)) * 1024 + hbase * 2) = st;
    }
  }

#pragma unroll
  for (int m = 16; m < 64; m <<= 1) {
#pragma unroll
    for (int cf = 0; cf < 4; ++cf) {
      s[cf] += __shfl_xor(s[cf], m);
      q[cf] += __shfl_xor(q[cf], m);
    }
  }
  if (ln < 16) {
#pragma unroll
    for (int cf = 0; cf < 4; ++cf) { red_s[w][cf][ln] = s[cf]; red_q[w][cf][ln] = q[cf]; }
  }
  __syncthreads();
  if (tid < 64) {
    const int cf = tid >> 4, li = tid & 15;
    float ts = 0.f, tq = 0.f;
#pragma unroll
    for (int ww = 0; ww < 4; ++ww) { ts += red_s[ww][cf][li]; tq += red_q[ww][cf][li]; }
    sum1[b * Ln + l0 + tid] = ts;
    sumsq1[b * Ln + l0 + tid] = tq;
  }
}

// ---------------- k2: causal scan -> mean/rstd ----------------
__global__ void k2_scan(const float* __restrict__ sum, const float* __restrict__ sumsq,
                        float* __restrict__ mean, float* __restrict__ rstd)
{
  const int b = blockIdx.x;
  const int tid = threadIdx.x;
  const int lane = tid & 63;
  const int wid = tid >> 6;
  __shared__ float wsm[4], wq[4];
  __shared__ float carry[2];
  if (tid == 0) { carry[0] = 0.f; carry[1] = 0.f; }
  __syncthreads();
  for (int base = 0; base < Ln; base += 256) {
    const int l = base + tid;
    float v = (l < Ln) ? sum[b * Ln + l] : 0.f;
    float q = (l < Ln) ? sumsq[b * Ln + l] : 0.f;
#pragma unroll
    for (int off = 1; off < 64; off <<= 1) {
      float tv = __shfl_up(v, off);
      float tq = __shfl_up(q, off);
      if (lane >= off) { v += tv; q += tq; }
    }
    if (lane == 63) { wsm[wid] = v; wq[wid] = q; }
    __syncthreads();
    float cs = carry[0], cq = carry[1];
    for (int ww = 0; ww < wid; ++ww) { cs += wsm[ww]; cq += wq[ww]; }
    v += cs; q += cq;
    if (l < Ln) {
      float cnt = 512.f * (float)(l + 1);
      float mn = v / cnt;
      float var = q / cnt - mn * mn;
      var = fmaxf(var, 0.f);
      mean[b * Ln + l] = mn;
      rstd[b * Ln + l] = rsqrtf(var + EPSf);
    }
    __syncthreads();
    if (tid == 0) {
      carry[0] += wsm[0] + wsm[1] + wsm[2] + wsm[3];
      carry[1] += wq[0] + wq[1] + wq[2] + wq[3];
    }
    __syncthreads();
  }
}

// ---------------- k3: g = prelu(dwconv(cln1(h))); hT -> gT (pre-swizzled) + sums ----------------
__global__ __launch_bounds__(256, 2)
void k3_conv(const u16* __restrict__ hT, const float* __restrict__ mean1,
             const float* __restrict__ rstd1, const float* __restrict__ dw,
             const float* __restrict__ db, const float* __restrict__ a2p,
             u16* __restrict__ gT, float* __restrict__ sum2, float* __restrict__ sumsq2)
{
  __shared__ char hTs[73728];       // 72 rows x 1KB
  __shared__ float m1s[72], r1s[72];
  const int bidx = blockIdx.x;
  const int b = bidx / 125;
  const int l0 = (bidx % 125) * 64;
  const int tid = threadIdx.x;
  const int ln = tid & 63, w = tid >> 6;

  for (int i = 0; i < 18; ++i) {
    int chunk = w * 18 + i;
    int lr = l0 - 4 + chunk;
    int lc = lr < 0 ? 0 : (lr > Ln - 1 ? Ln - 1 : lr);
    gl16((const char*)hT + ((size_t)(b * Ln + lc)) * 1024 + ln * 16, hTs + chunk * 1024);
  }
  if (tid < 72) {
    int lr = l0 - 4 + tid;
    bool ok = (lr >= 0) && (lr < Ln);
    m1s[tid] = ok ? mean1[b * Ln + lr] : 0.f;
    r1s[tid] = ok ? rstd1[b * Ln + lr] : 0.f;
  }
  // per-thread dw/db for its 8 channels (h = ln*8..+7)
  float d0[8], d1[8], d2[8], dbv[8];
#pragma unroll
  for (int e = 0; e < 8; ++e) {
    int hh = ln * 8 + e;
    d0[e] = dw[hh * 3 + 0]; d1[e] = dw[hh * 3 + 1]; d2[e] = dw[hh * 3 + 2];
    dbv[e] = db[hh];
  }
  const float a2v = a2p[0];
  __syncthreads();

  for (int it = 0; it < 16; ++it) {
    const int llo = w * 16 + it;      // local out row 0..63
    const int l = l0 + llo;
    uint4 t0 = *reinterpret_cast<const uint4*>(hTs + (size_t)(llo) * 1024 + ln * 16);
    uint4 t1 = *reinterpret_cast<const uint4*>(hTs + (size_t)(llo + 4) * 1024 + ln * 16);
    uint4 t2 = *reinterpret_cast<const uint4*>(hTs + (size_t)(llo + 8) * 1024 + ln * 16);
    const float m0 = m1s[llo],     rr0 = r1s[llo];
    const float mC = m1s[llo + 4], rrC = r1s[llo + 4];
    const float m2v = m1s[llo + 8], rr2 = r1s[llo + 8];
    const u32* p0 = reinterpret_cast<const u32*>(&t0);
    const u32* p1 = reinterpret_cast<const u32*>(&t1);
    const u32* p2 = reinterpret_cast<const u32*>(&t2);
    float sv = 0.f, qv = 0.f;
    u32 outw[4];
#pragma unroll
    for (int pp = 0; pp < 4; ++pp) {
      float v01[2];
#pragma unroll
      for (int hi = 0; hi < 2; ++hi) {
        int e = pp * 2 + hi;
        u32 a0 = hi ? (p0[pp] >> 16) : (p0[pp] & 0xffffu);
        u32 a1b = hi ? (p1[pp] >> 16) : (p1[pp] & 0xffffu);
        u32 a2b = hi ? (p2[pp] >> 16) : (p2[pp] & 0xffffu);
        float nh0 = (bf2f(a0) - m0) * rr0;
        float nh1 = (bf2f(a1b) - mC) * rrC;
        float nh2 = (bf2f(a2b) - m2v) * rr2;
        float v = fmaf(d0[e], nh0, fmaf(d1[e], nh1, fmaf(d2[e], nh2, dbv[e])));
        v = v >= 0.f ? v : a2v * v;
        sv += v; qv += v * v;
        v01[hi] = v;
      }
      outw[pp] = f2bf(v01[0]) | (f2bf(v01[1]) << 16);
    }
    uint4 st; st.x = outw[0]; st.y = outw[1]; st.z = outw[2]; st.w = outw[3];
    *reinterpret_cast<uint4*>((char*)gT + ((size_t)(b * Ln + l)) * 1024 +
                              (((ln * 16) ^ ((l & 7) << 4)))) = st;
#pragma unroll
    for (int off = 1; off < 64; off <<= 1) {
      sv += __shfl_xor(sv, off);
      qv += __shfl_xor(qv, off);
    }
    if (ln == 0) {
      sum2[b * Ln + l] = sv;
      sumsq2[b * Ln + l] = qv;
    }
  }
}

// ---------------- k5: out/skip = Wcat@g (MFMA) with folded cln2 + residual ----------------
__global__ __launch_bounds__(256, 2)
void k5_gemm2(const u16* __restrict__ gT, const u16* __restrict__ Wcatb,
              const float* __restrict__ Wsum, const float* __restrict__ bout,
              const float* __restrict__ bskip, const float* __restrict__ mean2,
              const float* __restrict__ rstd2, const float* __restrict__ x,
              float* __restrict__ outp)
{
  __shared__ char Ab[2][32768];
  __shared__ char Bb[2][8192];
  const int bidx = blockIdx.x;
  const int b = bidx / 125;
  const int l0 = (bidx % 125) * 64;
  const int tid = threadIdx.x;
  const int ln = tid & 63, w = tid >> 6;
  const int ln15 = ln & 15, lq = ln >> 4;

  // staging helper (per K-tile kt into buffer bi)
  auto stage = [&](int kt, int bi) {
    const char* Asrc = (const char*)Wcatb + kt * 32768;
#pragma unroll
    for (int i = 0; i < 8; ++i) {
      int chunk = w * 8 + i;
      gl16(Asrc + chunk * 1024 + ln * 16, Ab[bi] + chunk * 1024);
    }
#pragma unroll
    for (int j = 0; j < 2; ++j) {
      int chunk = w * 2 + j;
      int lrow = chunk * 8 + (ln >> 3);
      int pos = (ln & 7) * 16;
      gl16((const char*)gT + ((size_t)(b * Ln + l0 + lrow)) * 1024 + kt * 128 + pos,
           Bb[bi] + chunk * 1024);
    }
  };

  f32x4 acc[4][4];
  const f32x4 z4 = {0.f, 0.f, 0.f, 0.f};
#pragma unroll
  for (int i = 0; i < 4; ++i)
#pragma unroll
    for (int j = 0; j < 4; ++j) acc[i][j] = z4;

  const int c0w = w * 64;
  stage(0, 0);
  __syncthreads();
  for (int kt = 0; kt < 8; ++kt) {
    const int cur = kt & 1;
    if (kt < 7) stage(kt + 1, cur ^ 1);
    const char* Ac = Ab[cur];
    const char* Bc = Bb[cur];
#pragma unroll
    for (int ks = 0; ks < 2; ++ks) {
      bf16x8 bfr[4];
#pragma unroll
      for (int cf = 0; cf < 4; ++cf) {
        int brow = cf * 16 + ln15;
        int off = ((ks * 64 + lq * 16) ^ ((brow & 7) << 4));
        bfr[cf] = *reinterpret_cast<const bf16x8*>(Bc + brow * 128 + off);
      }
#pragma unroll
      for (int rf = 0; rf < 4; ++rf) {
        int arow = c0w + rf * 16 + ln15;
        int aoff = ((ks * 64 + lq * 16) ^ ((arow & 7) << 4));
        bf16x8 afr = *reinterpret_cast<const bf16x8*>(Ac + arow * 128 + aoff);
#pragma unroll
        for (int cf = 0; cf < 4; ++cf)
          acc[rf][cf] = __builtin_amdgcn_mfma_f32_16x16x32_bf16(afr, bfr[cf], acc[rf][cf], 0, 0, 0);
      }
    }
    __syncthreads();
  }

  // epilogue
  float wsr[4][4], bir[4][4];
#pragma unroll
  for (int rf = 0; rf < 4; ++rf)
#pragma unroll
    for (int r = 0; r < 4; ++r) {
      int c = c0w + rf * 16 + lq * 4 + r;
      wsr[rf][r] = Wsum[c];
      bir[rf][r] = (c < Cn) ? bout[c] : bskip[c - Cn];
    }
  const size_t OUTOFF = (size_t)Bn * Cn * Ln;
#pragma unroll
  for (int cf = 0; cf < 4; ++cf) {
    const int l = l0 + cf * 16 + ln15;
    const float m2 = mean2[b * Ln + l];
    const float r2 = rstd2[b * Ln + l];
#pragma unroll
    for (int rf = 0; rf < 4; ++rf) {
#pragma unroll
      for (int r = 0; r < 4; ++r) {
        int c = c0w + rf * 16 + lq * 4 + r;
        float o = r2 * (acc[rf][cf][r] - m2 * wsr[rf][r]) + bir[rf][r];
        if (c < Cn) {
          o += x[((size_t)(b * Cn + c)) * Ln + l];
          outp[((size_t)(b * Cn + c)) * Ln + l] = o;
        } else {
          outp[OUTOFF + ((size_t)(b * Cn + (c - Cn))) * Ln + l] = o;
        }
      }
    }
  }
}

extern "C" void kernel_launch(void* const* d_in, const int* in_sizes, int n_in,
                              void* d_out, int out_size, void* d_ws, size_t ws_size,
                              hipStream_t stream)
{
  const float* x     = (const float*)d_in[0];
  const float* W1    = (const float*)d_in[1];
  const float* b1    = (const float*)d_in[2];
  const float* dw    = (const float*)d_in[3];
  const float* db    = (const float*)d_in[4];
  const float* Wout  = (const float*)d_in[5];
  const float* bout  = (const float*)d_in[6];
  const float* Wskip = (const float*)d_in[7];
  const float* bskip = (const float*)d_in[8];
  const float* a1    = (const float*)d_in[9];
  const float* a2    = (const float*)d_in[10];
  float* outp = (float*)d_out;

  char* ws = (char*)d_ws;
  u16* hT     = (u16*)(ws);                  // 32,768,000 B
  u16* gT     = (u16*)(ws + 32768000);       // 32,768,000 B (xTb aliases its head)
  u16* xTb    = (u16*)(ws + 32768000);       // 8,192,000 B, dead after k1
  u16* W1b    = (u16*)(ws + 65536000);       // 131,072 B
  u16* Wcatb  = (u16*)(ws + 65667072);       // 262,144 B
  float* Wsum   = (float*)(ws + 65929216);   // 1,024 B
  float* sum1   = (float*)(ws + 65930240);
  float* sumsq1 = (float*)(ws + 66058240);
  float* mean1  = (float*)(ws + 66186240);
  float* rstd1  = (float*)(ws + 66314240);
  float* sum2   = (float*)(ws + 66442240);
  float* sumsq2 = (float*)(ws + 66570240);
  float* mean2  = (float*)(ws + 66698240);
  float* rstd2  = (float*)(ws + 66826240);
  (void)in_sizes; (void)n_in; (void)out_size; (void)ws_size;

  hipLaunchKernelGGL(k0_prep, dim3(193), dim3(256), 0, stream,
                     W1, Wout, Wskip, W1b, Wcatb, Wsum);
  hipLaunchKernelGGL(ktr, dim3(Bn * 125), dim3(256), 0, stream, x, xTb);
  hipLaunchKernelGGL(k1_gemm1, dim3(Bn * 125), dim3(256), 0, stream,
                     xTb, W1b, b1, a1, hT, sum1, sumsq1);
  hipLaunchKernelGGL(k2_scan, dim3(Bn), dim3(256), 0, stream,
                     sum1, sumsq1, mean1, rstd1);
  hipLaunchKernelGGL(k3_conv, dim3(Bn * 125), dim3(256), 0, stream,
                     hT, mean1, rstd1, dw, db, a2, gT, sum2, sumsq2);
  hipLaunchKernelGGL(k2_scan, dim3(Bn), dim3(256), 0, stream,
                     sum2, sumsq2, mean2, rstd2);
  hipLaunchKernelGGL(k5_gemm2, dim3(Bn * 125), dim3(256), 0, stream,
                     gT, Wcatb, Wsum, bout, bskip, mean2, rstd2, x, outp);
}

// Round 3
// 90.410 us; speedup vs baseline: 3.3293x; 1.8006x over previous
//
#include <hip/hip_runtime.h>

typedef unsigned short u16;
typedef unsigned int u32;
typedef __attribute__((ext_vector_type(8))) short bf16x8;
typedef __attribute__((ext_vector_type(4))) float f32x4;

#define Bn 4
#define Cn 128
#define Hn 512
#define Ln 8000
#define EPSf 1e-8f

__device__ __forceinline__ float bf2f(u32 v) { return __uint_as_float(v << 16); }
__device__ __forceinline__ u32 f2bf(float f) {
  u32 u = __float_as_uint(f);
  return (u + 0x7fffu + ((u >> 16) & 1u)) >> 16;
}
__device__ __forceinline__ void gl16(const void* g, void* l) {
  __builtin_amdgcn_global_load_lds((const __attribute__((address_space(1))) u32*)g,
                                   (__attribute__((address_space(3))) u32*)l, 16, 0, 0);
}

// ---------------- k0: weight prep (bf16 + pre-swizzled images) ----------------
// W1b:  image [512 h][128 k] bf16, elem (h,k) at byte h*256 + ((k*2)^((h&7)<<4))
// Wcatb: per K-tile kt(8): [256 c][64 kk] bf16, byte kt*32768 + c*128 + ((kk*2)^((c&7)<<4))
__global__ void k0_prep(const float* __restrict__ W1, const float* __restrict__ Wout,
                        const float* __restrict__ Wskip,
                        u16* __restrict__ W1b, u16* __restrict__ Wcatb,
                        float* __restrict__ Wsum)
{
  const int bid = blockIdx.x, tid = threadIdx.x;
  if (bid < 64) {
    const int base = (bid * 256 + tid) * 4;
#pragma unroll
    for (int t = 0; t < 4; ++t) {
      int i = base + t;            // 0..65535
      int h = i >> 7, k = i & 127;
      int dbyte = h * 256 + (((k * 2) ^ ((h & 7) << 4)));
      W1b[dbyte >> 1] = (u16)f2bf(W1[h * Cn + k]);
    }
  } else if (bid < 192) {
    const int base = ((bid - 64) * 256 + tid) * 4;
#pragma unroll
    for (int t = 0; t < 4; ++t) {
      int j = base + t;            // 0..131071
      int kt = j >> 14, r = j & 16383, c = r >> 6, kk = r & 63;
      int k = kt * 64 + kk;
      float v = (c < Cn) ? Wout[c * Hn + k] : Wskip[(c - Cn) * Hn + k];
      int dbyte = kt * 32768 + c * 128 + (((kk * 2) ^ ((c & 7) << 4)));
      Wcatb[dbyte >> 1] = (u16)f2bf(v);
    }
  } else {
    const int c = tid;
    const float* Wp = (c < Cn) ? (Wout + (size_t)c * Hn) : (Wskip + (size_t)(c - Cn) * Hn);
    float s = 0.f;
    for (int k = 0; k < Hn; ++k) s += Wp[k];
    Wsum[c] = s;
  }
}

// ---------------- k1: fused transpose + GEMM1 (h = prelu(W1@x+b1)) ----------------
// reads x directly, writes hT[b][l][512 h] bf16 (linear rows) + per-l sums
__global__ __launch_bounds__(256, 2)
void k1_fused(const float* __restrict__ x, const u16* __restrict__ W1b,
              const float* __restrict__ b1, const float* __restrict__ a1p,
              u16* __restrict__ hT, float* __restrict__ sum1, float* __restrict__ sumsq1)
{
  __shared__ char regA[32768];   // x f32 tile [128 c][256B], then W1 slice buffer
  __shared__ char xs[16384];     // [64 l][128 c bf16], 16B-unit swizzle by (l&7)
  __shared__ char stg[16384];    // 4 KB per wave store staging
  __shared__ float b1s[512];
  const int bidx = blockIdx.x;
  const int b = bidx / 125, l0 = (bidx % 125) * 64;
  const int tid = threadIdx.x, ln = tid & 63, w = tid >> 6;
  const int ln15 = ln & 15, lq = ln >> 4;

  {
    const char* xb = (const char*)x + ((size_t)b * Cn * Ln + l0) * 4;
#pragma unroll
    for (int i = 0; i < 8; ++i) {
      int chunk = w * 8 + i;                     // 0..31, 4 c-rows each
      gl16(xb + (size_t)(chunk * 4 + (ln >> 4)) * (Ln * 4) + (ln & 15) * 16,
           regA + chunk * 1024);
    }
  }
  b1s[tid] = b1[tid];
  b1s[tid + 256] = b1[tid + 256];
  __syncthreads();
  // transpose regA -> xs (bf16, swizzled)
#pragma unroll
  for (int p = 0; p < 4; ++p) {
    int u = tid + p * 256;
    int l = u & 63, ui = u >> 6;                 // ui 0..15
    u32 pk[4];
#pragma unroll
    for (int pp = 0; pp < 4; ++pp) {
      int c0 = ui * 8 + pp * 2;
      float f0 = *(const float*)(regA + c0 * 256 + l * 4);
      float f1 = *(const float*)(regA + (c0 + 1) * 256 + l * 4);
      pk[pp] = f2bf(f0) | (f2bf(f1) << 16);
    }
    uint4 st; st.x = pk[0]; st.y = pk[1]; st.z = pk[2]; st.w = pk[3];
    *(uint4*)(xs + l * 256 + ((ui * 16) ^ ((l & 7) << 4))) = st;
  }

  const float a1v = a1p[0];
  float sAcc = 0.f, qAcc = 0.f;

  for (int s = 0; s < 4; ++s) {
    __syncthreads();               // regA free (transpose / previous slice done)
#pragma unroll
    for (int i = 0; i < 8; ++i) {
      int chunk = w * 8 + i;
      gl16((const char*)W1b + s * 32768 + chunk * 1024 + ln * 16, regA + chunk * 1024);
    }
    __syncthreads();               // slice staged (barrier drains vmcnt)

    f32x4 acc[8];
    const f32x4 z4 = {0.f, 0.f, 0.f, 0.f};
#pragma unroll
    for (int rf = 0; rf < 8; ++rf) acc[rf] = z4;
#pragma unroll
    for (int kf = 0; kf < 4; ++kf) {
      const int brow = w * 16 + ln15;
      bf16x8 bfr = *(const bf16x8*)(xs + brow * 256 +
                                    ((kf * 64 + lq * 16) ^ ((brow & 7) << 4)));
#pragma unroll
      for (int rf = 0; rf < 8; ++rf) {
        int arow = rf * 16 + ln15;
        bf16x8 afr = *(const bf16x8*)(regA + arow * 256 +
                                      ((kf * 64 + lq * 16) ^ ((arow & 7) << 4)));
        acc[rf] = __builtin_amdgcn_mfma_f32_16x16x32_bf16(afr, bfr, acc[rf], 0, 0, 0);
      }
    }
    // epilogue: bias + prelu + sums; pack to stg (wave-private, swizzled)
#pragma unroll
    for (int rf = 0; rf < 8; ++rf) {
      int hb = s * 128 + rf * 16 + lq * 4;
      float v0 = acc[rf][0] + b1s[hb + 0]; v0 = v0 >= 0.f ? v0 : a1v * v0;
      float v1 = acc[rf][1] + b1s[hb + 1]; v1 = v1 >= 0.f ? v1 : a1v * v1;
      float v2 = acc[rf][2] + b1s[hb + 2]; v2 = v2 >= 0.f ? v2 : a1v * v2;
      float v3 = acc[rf][3] + b1s[hb + 3]; v3 = v3 >= 0.f ? v3 : a1v * v3;
      sAcc += v0 + v1 + v2 + v3;
      qAcc += v0 * v0 + v1 * v1 + v2 * v2 + v3 * v3;
      uint2 st2;
      st2.x = f2bf(v0) | (f2bf(v1) << 16);
      st2.y = f2bf(v2) | (f2bf(v3) << 16);
      *(uint2*)(stg + w * 4096 + ln15 * 256 +
                ((rf * 32 + lq * 8) ^ ((ln15 & 3) << 4))) = st2;
    }
    // coalesced 256B-chunk stores of wave's 16 rows
#pragma unroll
    for (int p = 0; p < 4; ++p) {
      int lr = p * 4 + (ln >> 4);
      int j = ln & 15;
      uint4 v = *(const uint4*)(stg + w * 4096 + lr * 256 + ((j * 16) ^ ((lr & 3) << 4)));
      *(uint4*)((char*)hT + ((size_t)(b * Ln + l0 + w * 16 + lr)) * 1024 +
                s * 256 + j * 16) = v;
    }
  }
  // per-l sums: reduce over the 4 lq lanes
  sAcc += __shfl_xor(sAcc, 16); qAcc += __shfl_xor(qAcc, 16);
  sAcc += __shfl_xor(sAcc, 32); qAcc += __shfl_xor(qAcc, 32);
  if (lq == 0) {
    sum1[b * Ln + l0 + w * 16 + ln15] = sAcc;
    sumsq1[b * Ln + l0 + w * 16 + ln15] = qAcc;
  }
}

// ---------------- k2: causal scan -> mean/rstd (single-pass, register-blocked) ----------------
__global__ void k2_scan(const float* __restrict__ sum, const float* __restrict__ sumsq,
                        float* __restrict__ mean, float* __restrict__ rstd)
{
  const int b = blockIdx.x, tid = threadIdx.x;
  const int lane = tid & 63, w = tid >> 6;
  __shared__ float wts[4], wtq[4];
  float v[32], q[32];
  float ts = 0.f, tq = 0.f;
  const int base = tid * 32;                    // threads 0..249 cover 8000
  const bool act = (tid < 250);
  if (act) {
#pragma unroll
    for (int i = 0; i < 8; ++i) {
      float4 a = *(const float4*)(sum + (size_t)b * Ln + base + i * 4);
      float4 c = *(const float4*)(sumsq + (size_t)b * Ln + base + i * 4);
      v[i * 4 + 0] = a.x; v[i * 4 + 1] = a.y; v[i * 4 + 2] = a.z; v[i * 4 + 3] = a.w;
      q[i * 4 + 0] = c.x; q[i * 4 + 1] = c.y; q[i * 4 + 2] = c.z; q[i * 4 + 3] = c.w;
    }
#pragma unroll
    for (int i = 0; i < 32; ++i) { ts += v[i]; tq += q[i]; }
  }
  float is = ts, iq = tq;
#pragma unroll
  for (int off = 1; off < 64; off <<= 1) {
    float a = __shfl_up(is, off);
    float c = __shfl_up(iq, off);
    if (lane >= off) { is += a; iq += c; }
  }
  float es = is - ts, eq = iq - tq;             // exclusive prefix within wave
  if (lane == 63) { wts[w] = is; wtq[w] = iq; }
  __syncthreads();
  for (int ww = 0; ww < w; ++ww) { es += wts[ww]; eq += wtq[ww]; }
  if (act) {
    float rs = es, rq = eq;
#pragma unroll
    for (int i = 0; i < 32; ++i) {
      rs += v[i]; rq += q[i];
      float cnt = 512.f * (float)(base + i + 1);
      float mn = rs / cnt;
      float var = fmaxf(rq / cnt - mn * mn, 0.f);
      v[i] = mn;
      q[i] = rsqrtf(var + EPSf);
    }
#pragma unroll
    for (int i = 0; i < 8; ++i) {
      float4 a; a.x = v[i*4+0]; a.y = v[i*4+1]; a.z = v[i*4+2]; a.w = v[i*4+3];
      float4 c; c.x = q[i*4+0]; c.y = q[i*4+1]; c.z = q[i*4+2]; c.w = q[i*4+3];
      *(float4*)(mean + (size_t)b * Ln + base + i * 4) = a;
      *(float4*)(rstd + (size_t)b * Ln + base + i * 4) = c;
    }
  }
}

// ---------------- k3: g = prelu(dwconv(cln1(h))); hT -> gT (pre-swizzled) + sums ----------------
__global__ __launch_bounds__(256, 2)
void k3_conv(const u16* __restrict__ hT, const float* __restrict__ mean1,
             const float* __restrict__ rstd1, const float* __restrict__ dw,
             const float* __restrict__ db, const float* __restrict__ a2p,
             u16* __restrict__ gT, float* __restrict__ sum2, float* __restrict__ sumsq2)
{
  __shared__ char hTs[73728];       // 72 rows x 1KB
  __shared__ float m1s[72], r1s[72];
  const int bidx = blockIdx.x;
  const int b = bidx / 125;
  const int l0 = (bidx % 125) * 64;
  const int tid = threadIdx.x;
  const int ln = tid & 63, w = tid >> 6;

  for (int i = 0; i < 18; ++i) {
    int chunk = w * 18 + i;
    int lr = l0 - 4 + chunk;
    int lc = lr < 0 ? 0 : (lr > Ln - 1 ? Ln - 1 : lr);
    gl16((const char*)hT + ((size_t)(b * Ln + lc)) * 1024 + ln * 16, hTs + chunk * 1024);
  }
  if (tid < 72) {
    int lr = l0 - 4 + tid;
    bool ok = (lr >= 0) && (lr < Ln);
    m1s[tid] = ok ? mean1[b * Ln + lr] : 0.f;
    r1s[tid] = ok ? rstd1[b * Ln + lr] : 0.f;
  }
  float d0[8], d1[8], d2[8], dbv[8];
#pragma unroll
  for (int e = 0; e < 8; ++e) {
    int hh = ln * 8 + e;
    d0[e] = dw[hh * 3 + 0]; d1[e] = dw[hh * 3 + 1]; d2[e] = dw[hh * 3 + 2];
    dbv[e] = db[hh];
  }
  const float a2v = a2p[0];
  __syncthreads();

  for (int it = 0; it < 16; ++it) {
    const int llo = w * 16 + it;      // local out row 0..63
    const int l = l0 + llo;
    uint4 t0 = *reinterpret_cast<const uint4*>(hTs + (size_t)(llo) * 1024 + ln * 16);
    uint4 t1 = *reinterpret_cast<const uint4*>(hTs + (size_t)(llo + 4) * 1024 + ln * 16);
    uint4 t2 = *reinterpret_cast<const uint4*>(hTs + (size_t)(llo + 8) * 1024 + ln * 16);
    const float m0 = m1s[llo],     rr0 = r1s[llo];
    const float mC = m1s[llo + 4], rrC = r1s[llo + 4];
    const float m2v = m1s[llo + 8], rr2 = r1s[llo + 8];
    const u32* p0 = reinterpret_cast<const u32*>(&t0);
    const u32* p1 = reinterpret_cast<const u32*>(&t1);
    const u32* p2 = reinterpret_cast<const u32*>(&t2);
    float sv = 0.f, qv = 0.f;
    u32 outw[4];
#pragma unroll
    for (int pp = 0; pp < 4; ++pp) {
      float v01[2];
#pragma unroll
      for (int hi = 0; hi < 2; ++hi) {
        int e = pp * 2 + hi;
        u32 a0 = hi ? (p0[pp] >> 16) : (p0[pp] & 0xffffu);
        u32 a1b = hi ? (p1[pp] >> 16) : (p1[pp] & 0xffffu);
        u32 a2b = hi ? (p2[pp] >> 16) : (p2[pp] & 0xffffu);
        float nh0 = (bf2f(a0) - m0) * rr0;
        float nh1 = (bf2f(a1b) - mC) * rrC;
        float nh2 = (bf2f(a2b) - m2v) * rr2;
        float vv = fmaf(d0[e], nh0, fmaf(d1[e], nh1, fmaf(d2[e], nh2, dbv[e])));
        vv = vv >= 0.f ? vv : a2v * vv;
        sv += vv; qv += vv * vv;
        v01[hi] = vv;
      }
      outw[pp] = f2bf(v01[0]) | (f2bf(v01[1]) << 16);
    }
    uint4 st; st.x = outw[0]; st.y = outw[1]; st.z = outw[2]; st.w = outw[3];
    *reinterpret_cast<uint4*>((char*)gT + ((size_t)(b * Ln + l)) * 1024 +
                              (((ln * 16) ^ ((l & 7) << 4)))) = st;
#pragma unroll
    for (int off = 1; off < 64; off <<= 1) {
      sv += __shfl_xor(sv, off);
      qv += __shfl_xor(qv, off);
    }
    if (ln == 0) {
      sum2[b * Ln + l] = sv;
      sumsq2[b * Ln + l] = qv;
    }
  }
}

// ---------------- k5: out/skip = Wcat@g (MFMA) + folded cln2 + residual ----------------
__global__ __launch_bounds__(256, 2)
void k5_gemm2(const u16* __restrict__ gT, const u16* __restrict__ Wcatb,
              const float* __restrict__ Wsum, const float* __restrict__ bout,
              const float* __restrict__ bskip, const float* __restrict__ mean2,
              const float* __restrict__ rstd2, const float* __restrict__ x,
              float* __restrict__ outp)
{
  __shared__ char Ab[2][32768];
  __shared__ char Bb[2][8192];
  const int bidx = blockIdx.x;
  const int b = bidx / 125;
  const int l0 = (bidx % 125) * 64;
  const int tid = threadIdx.x;
  const int ln = tid & 63, w = tid >> 6;
  const int ln15 = ln & 15, lq = ln >> 4;

  auto stage = [&](int kt, int bi) {
    const char* Asrc = (const char*)Wcatb + kt * 32768;
#pragma unroll
    for (int i = 0; i < 8; ++i) {
      int chunk = w * 8 + i;
      gl16(Asrc + chunk * 1024 + ln * 16, Ab[bi] + chunk * 1024);
    }
#pragma unroll
    for (int j = 0; j < 2; ++j) {
      int chunk = w * 2 + j;
      int lrow = chunk * 8 + (ln >> 3);
      int pos = (ln & 7) * 16;
      gl16((const char*)gT + ((size_t)(b * Ln + l0 + lrow)) * 1024 + kt * 128 + pos,
           Bb[bi] + chunk * 1024);
    }
  };

  f32x4 acc[4][4];
  const f32x4 z4 = {0.f, 0.f, 0.f, 0.f};
#pragma unroll
  for (int i = 0; i < 4; ++i)
#pragma unroll
    for (int j = 0; j < 4; ++j) acc[i][j] = z4;

  const int c0w = w * 64;
  stage(0, 0);
  __syncthreads();
  for (int kt = 0; kt < 8; ++kt) {
    const int cur = kt & 1;
    if (kt < 7) stage(kt + 1, cur ^ 1);
    const char* Ac = Ab[cur];
    const char* Bc = Bb[cur];
#pragma unroll
    for (int ks = 0; ks < 2; ++ks) {
      bf16x8 bfr[4];
#pragma unroll
      for (int cf = 0; cf < 4; ++cf) {
        int brow = cf * 16 + ln15;
        int off = ((ks * 64 + lq * 16) ^ ((brow & 7) << 4));
        bfr[cf] = *reinterpret_cast<const bf16x8*>(Bc + brow * 128 + off);
      }
#pragma unroll
      for (int rf = 0; rf < 4; ++rf) {
        int arow = c0w + rf * 16 + ln15;
        int aoff = ((ks * 64 + lq * 16) ^ ((arow & 7) << 4));
        bf16x8 afr = *reinterpret_cast<const bf16x8*>(Ac + arow * 128 + aoff);
#pragma unroll
        for (int cf = 0; cf < 4; ++cf)
          acc[rf][cf] = __builtin_amdgcn_mfma_f32_16x16x32_bf16(afr, bfr[cf], acc[rf][cf], 0, 0, 0);
      }
    }
    __syncthreads();
  }

  // fold cln2 + biases; stage f32 tile [256 c][64 l] into freed Ab (swizzled)
  float wsr[4][4], bir[4][4];
#pragma unroll
  for (int rf = 0; rf < 4; ++rf)
#pragma unroll
    for (int r = 0; r < 4; ++r) {
      int c = c0w + rf * 16 + lq * 4 + r;
      wsr[rf][r] = Wsum[c];
      bir[rf][r] = (c < Cn) ? bout[c] : bskip[c - Cn];
    }
  char* stg = &Ab[0][0];
#pragma unroll
  for (int cf = 0; cf < 4; ++cf) {
    const int ll = cf * 16 + ln15;
    const int l = l0 + ll;
    const float m2 = mean2[b * Ln + l];
    const float r2 = rstd2[b * Ln + l];
#pragma unroll
    for (int rf = 0; rf < 4; ++rf) {
#pragma unroll
      for (int r = 0; r < 4; ++r) {
        int c = c0w + rf * 16 + lq * 4 + r;
        float o = r2 * (acc[rf][cf][r] - m2 * wsr[rf][r]) + bir[rf][r];
        *(float*)(stg + c * 256 + ((((ll >> 2) * 16) ^ ((c & 7) << 4)) + (ll & 3) * 4)) = o;
      }
    }
  }
  __syncthreads();
  // coalesced store pass: 256 rows x 256B, vectorized residual
  const size_t OUTOFF = (size_t)Bn * Cn * Ln;
#pragma unroll
  for (int p = 0; p < 16; ++p) {
    int i = p * 256 + tid;
    int c = i >> 4, j = i & 15;
    float4 v = *(const float4*)(stg + c * 256 + ((j * 16) ^ ((c & 7) << 4)));
    if (c < Cn) {
      float4 xv = *(const float4*)(x + ((size_t)(b * Cn + c)) * Ln + l0 + j * 4);
      v.x += xv.x; v.y += xv.y; v.z += xv.z; v.w += xv.w;
      *(float4*)(outp + ((size_t)(b * Cn + c)) * Ln + l0 + j * 4) = v;
    } else {
      *(float4*)(outp + OUTOFF + ((size_t)(b * Cn + c - Cn)) * Ln + l0 + j * 4) = v;
    }
  }
}

extern "C" void kernel_launch(void* const* d_in, const int* in_sizes, int n_in,
                              void* d_out, int out_size, void* d_ws, size_t ws_size,
                              hipStream_t stream)
{
  const float* x     = (const float*)d_in[0];
  const float* W1    = (const float*)d_in[1];
  const float* b1    = (const float*)d_in[2];
  const float* dw    = (const float*)d_in[3];
  const float* db    = (const float*)d_in[4];
  const float* Wout  = (const float*)d_in[5];
  const float* bout  = (const float*)d_in[6];
  const float* Wskip = (const float*)d_in[7];
  const float* bskip = (const float*)d_in[8];
  const float* a1    = (const float*)d_in[9];
  const float* a2    = (const float*)d_in[10];
  float* outp = (float*)d_out;

  char* ws = (char*)d_ws;
  u16* hT     = (u16*)(ws);                  // 32,768,000 B
  u16* gT     = (u16*)(ws + 32768000);       // 32,768,000 B
  u16* W1b    = (u16*)(ws + 65536000);       // 131,072 B
  u16* Wcatb  = (u16*)(ws + 65667072);       // 262,144 B
  float* Wsum   = (float*)(ws + 65929216);   // 1,024 B
  float* sum1   = (float*)(ws + 65930240);
  float* sumsq1 = (float*)(ws + 66058240);
  float* mean1  = (float*)(ws + 66186240);
  float* rstd1  = (float*)(ws + 66314240);
  float* sum2   = (float*)(ws + 66442240);
  float* sumsq2 = (float*)(ws + 66570240);
  float* mean2  = (float*)(ws + 66698240);
  float* rstd2  = (float*)(ws + 66826240);
  (void)in_sizes; (void)n_in; (void)out_size; (void)ws_size;

  hipLaunchKernelGGL(k0_prep, dim3(193), dim3(256), 0, stream,
                     W1, Wout, Wskip, W1b, Wcatb, Wsum);
  hipLaunchKernelGGL(k1_fused, dim3(Bn * 125), dim3(256), 0, stream,
                     x, W1b, b1, a1, hT, sum1, sumsq1);
  hipLaunchKernelGGL(k2_scan, dim3(Bn), dim3(256), 0, stream,
                     sum1, sumsq1, mean1, rstd1);
  hipLaunchKernelGGL(k3_conv, dim3(Bn * 125), dim3(256), 0, stream,
                     hT, mean1, rstd1, dw, db, a2, gT, sum2, sumsq2);
  hipLaunchKernelGGL(k2_scan, dim3(Bn), dim3(256), 0, stream,
                     sum2, sumsq2, mean2, rstd2);
  hipLaunchKernelGGL(k5_gemm2, dim3(Bn * 125), dim3(256), 0, stream,
                     gT, Wcatb, Wsum, bout, bskip, mean2, rstd2, x, outp);
}